// Round 3
// baseline (1394.159 us; speedup 1.0000x reference)
//
#include <hip/hip_runtime.h>
#include <stdint.h>

// Problem constants: B=4, S=2048, D=1024, E=8, F=4096, k=2 — ALL FP32 I/O
#define T_TOK   8192
#define DMODEL  1024
#define NEXP    8
#define FFN     4096
#define TASSIGN 16384   // T_TOK * k

typedef unsigned short u16;
typedef __attribute__((ext_vector_type(8))) short short8;   // MFMA bf16 A/B frag
typedef __attribute__((ext_vector_type(8))) u16 u16x8;
typedef __attribute__((ext_vector_type(4))) u16 u16x4;
typedef __attribute__((ext_vector_type(4))) float f32x4;    // MFMA C/D frag

__device__ __forceinline__ float bf2f(u16 u) {
  union { unsigned int i; float f; } v; v.i = ((unsigned int)u) << 16; return v.f;
}
__device__ __forceinline__ u16 f2bf(float f) {
  union { float f; unsigned int i; } v; v.f = f;
  unsigned int x = v.i;
  x += 0x7fffu + ((x >> 16) & 1u);   // round-to-nearest-even
  return (u16)(x >> 16);
}
// jax.nn.gelu default: approximate=True (tanh form)
__device__ __forceinline__ float gelu_tanh(float x) {
  float z = 0.7978845608028654f * x * (1.0f + 0.044715f * x * x);
  float t = 1.0f - 2.0f / (__expf(2.0f * z) + 1.0f);
  return 0.5f * x * (1.0f + t);
}

// ---------------------------------------------------------------- meta init --
__global__ void init_kernel(int* __restrict__ meta) {
  if (threadIdx.x < 32) meta[threadIdx.x] = 0;
}

// ---------------------------------------------------------------- cast x ----
// xb = bf16(x), 4 elements/thread
__global__ void cast_x_kernel(const float* __restrict__ x, u16* __restrict__ xb) {
  int i = (blockIdx.x * 256 + threadIdx.x) * 4;
  float4 v = *(const float4*)(x + i);
  u16x4 o;
  o[0] = f2bf(v.x); o[1] = f2bf(v.y); o[2] = f2bf(v.z); o[3] = f2bf(v.w);
  *(u16x4*)(xb + i) = o;
}

// ---------------------------------------------------------------- gating ----
// One wave per token: logits = x[t] @ Wg  ([1024] x [1024,8]), top-2, softmax. FP32.
__global__ void gate_kernel(const float* __restrict__ x, const float* __restrict__ Wg,
                            int* __restrict__ topi, float* __restrict__ topw,
                            int* __restrict__ counts) {
  __shared__ float sWg[DMODEL * NEXP];   // 32 KB
  int tid = threadIdx.x;
  for (int i = tid; i < DMODEL * NEXP / 4; i += 256)
    ((float4*)sWg)[i] = ((const float4*)Wg)[i];
  __syncthreads();

  int wave = tid >> 6, lane = tid & 63;
  int t = blockIdx.x * 4 + wave;       // grid=2048 -> t < 8192 always

  float acc[NEXP] = {0, 0, 0, 0, 0, 0, 0, 0};
  const float* xr = x + (size_t)t * DMODEL;
  for (int d0 = 0; d0 < DMODEL; d0 += 128) {
    int d = d0 + lane * 2;
    float2 xx = *(const float2*)(xr + d);
    const float* g0 = sWg + (size_t)d * NEXP;
#pragma unroll
    for (int e = 0; e < NEXP; e++)
      acc[e] += xx.x * g0[e] + xx.y * g0[NEXP + e];
  }
#pragma unroll
  for (int off = 32; off > 0; off >>= 1)
#pragma unroll
    for (int e = 0; e < NEXP; e++)
      acc[e] += __shfl_xor(acc[e], off, 64);

  if (lane == 0) {
    float v0 = -1e30f, v1 = -1e30f; int i0 = 0, i1 = 0;
#pragma unroll
    for (int e = 0; e < NEXP; e++) {           // strict > keeps earliest index on ties
      float v = acc[e];
      if (v > v0) { v1 = v0; i1 = i0; v0 = v; i0 = e; }
      else if (v > v1) { v1 = v; i1 = e; }
    }
    float e1 = __expf(v1 - v0);                // v1 <= v0
    float s = 1.0f / (1.0f + e1);
    topi[t * 2] = i0; topi[t * 2 + 1] = i1;
    topw[t * 2] = s;  topw[t * 2 + 1] = e1 * s;   // fp32, no rounding (ref is fp32)
    atomicAdd(&counts[i0], 1);
    atomicAdd(&counts[i1], 1);
  }
}

__global__ void scan_kernel(const int* __restrict__ counts, int* __restrict__ offsets,
                            int* __restrict__ cursors) {
  if (threadIdx.x == 0) {
    int s = 0;
    for (int e = 0; e < NEXP; e++) { offsets[e] = s; s += counts[e]; }
    offsets[NEXP] = s;
  }
  if (threadIdx.x < NEXP) cursors[threadIdx.x] = 0;
}

__global__ void build_kernel(const int* __restrict__ topi, const int* __restrict__ offsets,
                             int* __restrict__ cursors, int* __restrict__ perm,
                             int* __restrict__ slotrow) {
  int t = blockIdx.x * blockDim.x + threadIdx.x;
  if (t >= T_TOK) return;
#pragma unroll
  for (int s = 0; s < 2; s++) {
    int e = topi[t * 2 + s];
    int p = atomicAdd(&cursors[e], 1);
    int g = offsets[e] + p;
    perm[g] = t;
    slotrow[t * 2 + s] = g;
  }
}

// ------------------------------------------------------------------ GEMM ----
// C[i,n] = sum_k Arow(i)[k] * B[e][k][n].  A is bf16 (xb or H); B is FP32 weights,
// converted to bf16 during the LDS repack.  C is bf16.
// GATHER: Arow(i) = A[perm[off+i]] (GEMM1);  else Arow(i) = A[off+i] (GEMM2)
// GELU:   apply gelu before store (GEMM1 -> H);  else plain store (GEMM2 -> Y)
// Tiles: BM=128, BN=128, BK=32. 4 waves, each owns a 64x64 quadrant (4x4 MFMA 16x16x32).
template <int K, int N, bool GATHER, bool GELU>
__global__ __launch_bounds__(256) void gemm_kernel(
    const u16* __restrict__ A, const float* __restrict__ B, u16* __restrict__ C,
    const int* __restrict__ offsets, const int* __restrict__ perm) {
  __shared__ u16 As[128 * 32];   // [row][k] 8 KB
  __shared__ u16 Bs[128 * 32];   // [n][k]   8 KB
  int e = blockIdx.z;
  int off = offsets[e];
  int nrows = offsets[e + 1] - off;
  int mtile = blockIdx.y;
  if (mtile * 128 >= nrows) return;   // block-uniform: safe before barriers
  int ntile = blockIdx.x;

  int tid = threadIdx.x;
  int wave = tid >> 6, lane = tid & 63;

  // ---- A staging coords: thread -> (row rr / rr+64, k-chunk kc) ----
  int rr = tid >> 2;             // 0..63
  int kc = (tid & 3) * 8;        // k-offset (elements) of the 16B chunk
  int m0 = mtile * 128 + rr;
  int mm0 = min(m0, nrows - 1);          // clamp: duplicates last valid row
  int mm1 = min(m0 + 64, nrows - 1);
  const u16 *arow0, *arow1;
  if (GATHER) {
    arow0 = A + (size_t)perm[off + mm0] * K + kc;
    arow1 = A + (size_t)perm[off + mm1] * K + kc;
  } else {
    arow0 = A + (size_t)(off + mm0) * K + kc;
    arow1 = A + (size_t)(off + mm1) * K + kc;
  }

  // ---- B staging coords: thread -> rows kk2,kk2+1 of the 32xK-tile, 8 n's ----
  int kk2 = (tid >> 4) * 2;      // even k in [0,32)
  int n8  = (tid & 15) * 8;      // n-offset in [0,128)
  const float* brow0 = B + (size_t)e * ((size_t)K * N) + (size_t)kk2 * N
                         + (size_t)ntile * 128 + n8;
  const float* brow1 = brow0 + N;

  int wm = (wave >> 1) * 64, wn = (wave & 1) * 64;
  int lm = lane & 15, kq = lane >> 4;

  f32x4 acc[4][4];
  f32x4 zero = {0.f, 0.f, 0.f, 0.f};
#pragma unroll
  for (int i = 0; i < 4; i++)
#pragma unroll
    for (int j = 0; j < 4; j++) acc[i][j] = zero;

  uint32_t* bs32 = (uint32_t*)Bs;
  for (int k0 = 0; k0 < K; k0 += 32) {
    // global loads into registers first (no LDS hazard yet)
    u16x8 av0 = *(const u16x8*)(arow0 + k0);
    u16x8 av1 = *(const u16x8*)(arow1 + k0);
    float4 b00 = *(const float4*)(brow0 + (size_t)k0 * N);
    float4 b01 = *(const float4*)(brow0 + (size_t)k0 * N + 4);
    float4 b10 = *(const float4*)(brow1 + (size_t)k0 * N);
    float4 b11 = *(const float4*)(brow1 + (size_t)k0 * N + 4);
    __syncthreads();   // previous iteration's LDS reads complete
    *(u16x8*)(As + (size_t)rr * 32 + kc) = av0;
    *(u16x8*)(As + (size_t)(rr + 64) * 32 + kc) = av1;
    // repack [k][n] -> [n][k]: word (n*16 + kk2/2) = bf16(k)|bf16(k+1)<<16
    int wcol = kk2 >> 1;
    bs32[(size_t)(n8 + 0) * 16 + wcol] = (uint32_t)f2bf(b00.x) | ((uint32_t)f2bf(b10.x) << 16);
    bs32[(size_t)(n8 + 1) * 16 + wcol] = (uint32_t)f2bf(b00.y) | ((uint32_t)f2bf(b10.y) << 16);
    bs32[(size_t)(n8 + 2) * 16 + wcol] = (uint32_t)f2bf(b00.z) | ((uint32_t)f2bf(b10.z) << 16);
    bs32[(size_t)(n8 + 3) * 16 + wcol] = (uint32_t)f2bf(b00.w) | ((uint32_t)f2bf(b10.w) << 16);
    bs32[(size_t)(n8 + 4) * 16 + wcol] = (uint32_t)f2bf(b01.x) | ((uint32_t)f2bf(b11.x) << 16);
    bs32[(size_t)(n8 + 5) * 16 + wcol] = (uint32_t)f2bf(b01.y) | ((uint32_t)f2bf(b11.y) << 16);
    bs32[(size_t)(n8 + 6) * 16 + wcol] = (uint32_t)f2bf(b01.z) | ((uint32_t)f2bf(b11.z) << 16);
    bs32[(size_t)(n8 + 7) * 16 + wcol] = (uint32_t)f2bf(b01.w) | ((uint32_t)f2bf(b11.w) << 16);
    __syncthreads();   // staged tile visible
    short8 a[4], b[4];
#pragma unroll
    for (int i = 0; i < 4; i++) {
      a[i] = *(const short8*)(As + (size_t)(wm + i * 16 + lm) * 32 + kq * 8);
      b[i] = *(const short8*)(Bs + (size_t)(wn + i * 16 + lm) * 32 + kq * 8);
    }
#pragma unroll
    for (int i = 0; i < 4; i++)
#pragma unroll
      for (int j = 0; j < 4; j++)
        acc[i][j] = __builtin_amdgcn_mfma_f32_16x16x32_bf16(a[i], b[j], acc[i][j], 0, 0, 0);
  }

  // C/D frag: col = lane&15, row = (lane>>4)*4 + reg
#pragma unroll
  for (int i = 0; i < 4; i++) {
    int rbase = mtile * 128 + wm + i * 16 + kq * 4;
#pragma unroll
    for (int r = 0; r < 4; r++) {
      int row = rbase + r;
      if (row < nrows) {
        u16* crow = C + (size_t)(off + row) * N + ntile * 128 + wn + lm;
#pragma unroll
        for (int j = 0; j < 4; j++) {
          float v = acc[i][j][r];
          if (GELU) v = gelu_tanh(v);
          crow[j * 16] = f2bf(v);
        }
      }
    }
  }
}

// --------------------------------------------------------------- combine ----
// out[t] = w0 * Y[row(t,0)] + w1 * Y[row(t,1)]   (fp32 output)
__global__ void combine_kernel(const u16* __restrict__ Y, const int* __restrict__ slotrow,
                               const float* __restrict__ topw, float* __restrict__ out) {
  int idx = blockIdx.x * 256 + threadIdx.x;   // 8192 tokens * 256 chunks of 4
  int t = idx >> 8;
  int c = (idx & 255) * 4;
  int g0 = slotrow[t * 2], g1 = slotrow[t * 2 + 1];
  float w0 = topw[t * 2], w1 = topw[t * 2 + 1];
  u16x4 y0 = *(const u16x4*)(Y + (size_t)g0 * DMODEL + c);
  u16x4 y1 = *(const u16x4*)(Y + (size_t)g1 * DMODEL + c);
  float4 o;
  o.x = w0 * bf2f(y0[0]) + w1 * bf2f(y1[0]);
  o.y = w0 * bf2f(y0[1]) + w1 * bf2f(y1[1]);
  o.z = w0 * bf2f(y0[2]) + w1 * bf2f(y1[2]);
  o.w = w0 * bf2f(y0[3]) + w1 * bf2f(y1[3]);
  *(float4*)(out + (size_t)t * DMODEL + c) = o;
}

// ---------------------------------------------------------------- launch ----
extern "C" void kernel_launch(void* const* d_in, const int* in_sizes, int n_in,
                              void* d_out, int out_size, void* d_ws, size_t ws_size,
                              hipStream_t stream) {
  const float* x  = (const float*)d_in[0];
  const float* Wg = (const float*)d_in[1];
  const float* w1 = (const float*)d_in[2];
  const float* w2 = (const float*)d_in[3];
  float* out = (float*)d_out;

  uint8_t* ws = (uint8_t*)d_ws;
  size_t o = 0;
  u16* H  = (u16*)(ws + o); o += (size_t)TASSIGN * FFN * 2;      // 128 MB
  u16* Y  = (u16*)(ws + o); o += (size_t)TASSIGN * DMODEL * 2;   //  32 MB
  u16* xb = (u16*)(ws + o); o += (size_t)T_TOK * DMODEL * 2;     //  16 MB
  int*   topi    = (int*)(ws + o);   o += (size_t)TASSIGN * 4;
  float* topw    = (float*)(ws + o); o += (size_t)TASSIGN * 4;
  int*   perm    = (int*)(ws + o);   o += (size_t)TASSIGN * 4;
  int*   slotrow = (int*)(ws + o);   o += (size_t)TASSIGN * 4;
  int*   meta    = (int*)(ws + o);   o += 4096;   // counts[8], offsets[9], cursors[8]
  int* counts = meta, *offsets = meta + 8, *cursors = meta + 17;

  init_kernel<<<1, 64, 0, stream>>>(meta);
  cast_x_kernel<<<T_TOK * DMODEL / 4 / 256, 256, 0, stream>>>(x, xb);
  gate_kernel<<<T_TOK / 4, 256, 0, stream>>>(x, Wg, topi, topw, counts);
  scan_kernel<<<1, 64, 0, stream>>>(counts, offsets, cursors);
  build_kernel<<<T_TOK / 256, 256, 0, stream>>>(topi, offsets, cursors, perm, slotrow);
  // GEMM1: H = gelu(gather(xb) @ w1[e]); grid y=64 covers worst-case n_e=8192
  gemm_kernel<DMODEL, FFN, true, true>
      <<<dim3(FFN / 128, 64, NEXP), 256, 0, stream>>>(xb, w1, H, offsets, perm);
  // GEMM2: Y = H @ w2[e]
  gemm_kernel<FFN, DMODEL, false, false>
      <<<dim3(DMODEL / 128, 64, NEXP), 256, 0, stream>>>(H, w2, Y, offsets, perm);
  combine_kernel<<<(T_TOK * DMODEL / 4) / 256, 256, 0, stream>>>(Y, slotrow, topw, out);
}

// Round 4
// 1040.821 us; speedup vs baseline: 1.3395x; 1.3395x over previous
//
#include <hip/hip_runtime.h>
#include <stdint.h>

// Problem constants: B=4, S=2048, D=1024, E=8, F=4096, k=2 — FP32 I/O, bf16 MFMA compute
#define T_TOK   8192
#define DMODEL  1024
#define NEXP    8
#define FFN     4096
#define TASSIGN 16384   // T_TOK * k

typedef unsigned short u16;
typedef __attribute__((ext_vector_type(8))) short short8;   // MFMA bf16 A/B frag
typedef __attribute__((ext_vector_type(8))) u16 u16x8;
typedef __attribute__((ext_vector_type(4))) u16 u16x4;
typedef __attribute__((ext_vector_type(4))) float f32x4;    // MFMA C/D frag

__device__ __forceinline__ float bf2f(u16 u) {
  union { unsigned int i; float f; } v; v.i = ((unsigned int)u) << 16; return v.f;
}
__device__ __forceinline__ u16 f2bf(float f) {
  union { float f; unsigned int i; } v; v.f = f;
  unsigned int x = v.i;
  x += 0x7fffu + ((x >> 16) & 1u);   // round-to-nearest-even
  return (u16)(x >> 16);
}
// jax.nn.gelu default: approximate=True (tanh form)
__device__ __forceinline__ float gelu_tanh(float x) {
  float z = 0.7978845608028654f * x * (1.0f + 0.044715f * x * x);
  float t = 1.0f - 2.0f / (__expf(2.0f * z) + 1.0f);
  return 0.5f * x * (1.0f + t);
}
// async global->LDS, 16B per lane; LDS dest is wave-uniform base + lane*16
__device__ __forceinline__ void async16(const void* g, void* l) {
  __builtin_amdgcn_global_load_lds((__attribute__((address_space(1))) void*)g,
                                   (__attribute__((address_space(3))) void*)l,
                                   16, 0, 0);
}

// ---------------------------------------------------------------- meta init --
__global__ void init_kernel(int* __restrict__ meta) {
  if (threadIdx.x < 32) meta[threadIdx.x] = 0;
}

// ---------------------------------------------------------------- gating ----
// One wave per token: logits = x[t] @ Wg, top-2, softmax (all fp32).
// Fused: also writes xb = bf16(x) while the row is in registers.
__global__ void gate_kernel(const float* __restrict__ x, const float* __restrict__ Wg,
                            int* __restrict__ topi, float* __restrict__ topw,
                            int* __restrict__ counts, u16* __restrict__ xb) {
  __shared__ float sWg[DMODEL * NEXP];   // 32 KB
  int tid = threadIdx.x;
  for (int i = tid; i < DMODEL * NEXP / 4; i += 256)
    ((float4*)sWg)[i] = ((const float4*)Wg)[i];
  __syncthreads();

  int wave = tid >> 6, lane = tid & 63;
  int t = blockIdx.x * 4 + wave;       // grid=2048 -> t < 8192 always

  float acc[NEXP] = {0, 0, 0, 0, 0, 0, 0, 0};
  const float* xr = x + (size_t)t * DMODEL;
  u16* xbr = xb + (size_t)t * DMODEL;
  for (int d0 = 0; d0 < DMODEL; d0 += 128) {
    int d = d0 + lane * 2;
    float2 xx = *(const float2*)(xr + d);
    *(uint32_t*)(xbr + d) = (uint32_t)f2bf(xx.x) | ((uint32_t)f2bf(xx.y) << 16);
    const float* g0 = sWg + (size_t)d * NEXP;
#pragma unroll
    for (int e = 0; e < NEXP; e++)
      acc[e] += xx.x * g0[e] + xx.y * g0[NEXP + e];
  }
#pragma unroll
  for (int off = 32; off > 0; off >>= 1)
#pragma unroll
    for (int e = 0; e < NEXP; e++)
      acc[e] += __shfl_xor(acc[e], off, 64);

  if (lane == 0) {
    float v0 = -1e30f, v1 = -1e30f; int i0 = 0, i1 = 0;
#pragma unroll
    for (int e = 0; e < NEXP; e++) {           // strict > keeps earliest index on ties
      float v = acc[e];
      if (v > v0) { v1 = v0; i1 = i0; v0 = v; i0 = e; }
      else if (v > v1) { v1 = v; i1 = e; }
    }
    float e1 = __expf(v1 - v0);                // v1 <= v0
    float s = 1.0f / (1.0f + e1);
    topi[t * 2] = i0; topi[t * 2 + 1] = i1;
    topw[t * 2] = s;  topw[t * 2 + 1] = e1 * s;
    atomicAdd(&counts[i0], 1);
    atomicAdd(&counts[i1], 1);
  }
}

__global__ void scan_kernel(const int* __restrict__ counts, int* __restrict__ offsets,
                            int* __restrict__ cursors) {
  if (threadIdx.x == 0) {
    int s = 0;
    for (int e = 0; e < NEXP; e++) { offsets[e] = s; s += counts[e]; }
    offsets[NEXP] = s;
  }
  if (threadIdx.x < NEXP) cursors[threadIdx.x] = 0;
}

__global__ void build_kernel(const int* __restrict__ topi, const int* __restrict__ offsets,
                             int* __restrict__ cursors, int* __restrict__ perm,
                             int* __restrict__ slotrow) {
  int t = blockIdx.x * blockDim.x + threadIdx.x;
  if (t >= T_TOK) return;
#pragma unroll
  for (int s = 0; s < 2; s++) {
    int e = topi[t * 2 + s];
    int p = atomicAdd(&cursors[e], 1);
    int g = offsets[e] + p;
    perm[g] = t;
    slotrow[t * 2 + s] = g;
  }
}

// ------------------------------------------------------------- transpose ----
// fp32 -> bf16 + transpose. z<8: w1[e] [D][F] -> w1t[e] [F][D];
// z>=8: w2[e] [F][D] -> w2t[e] [D][F].  64x64 tiles via LDS.
__global__ void transpose_kernel(const float* __restrict__ w1, const float* __restrict__ w2,
                                 u16* __restrict__ w1t, u16* __restrict__ w2t) {
  __shared__ u16 sh[64][72];   // +8 pad: keeps 16B store alignment, breaks bank stride
  int z = blockIdx.y;
  const float* src; u16* dst; int R, C;
  if (z < 8) { src = w1 + (size_t)z * (DMODEL * FFN); dst = w1t + (size_t)z * (FFN * DMODEL); R = DMODEL; C = FFN; }
  else       { src = w2 + (size_t)(z - 8) * (FFN * DMODEL); dst = w2t + (size_t)(z - 8) * (DMODEL * FFN); R = FFN; C = DMODEL; }
  int tilesC = C >> 6;
  int rt = blockIdx.x / tilesC, ct = blockIdx.x % tilesC;
  int tid = threadIdx.x;
#pragma unroll
  for (int i = 0; i < 2; i++) {
    int idx = i * 256 + tid;
    int r = idx >> 3, c8 = (idx & 7) * 8;
    const float* s = src + (size_t)(rt * 64 + r) * C + ct * 64 + c8;
    float4 v0 = *(const float4*)s, v1 = *(const float4*)(s + 4);
    u16* d = &sh[r][c8];
    d[0] = f2bf(v0.x); d[1] = f2bf(v0.y); d[2] = f2bf(v0.z); d[3] = f2bf(v0.w);
    d[4] = f2bf(v1.x); d[5] = f2bf(v1.y); d[6] = f2bf(v1.z); d[7] = f2bf(v1.w);
  }
  __syncthreads();
#pragma unroll
  for (int i = 0; i < 2; i++) {
    int idx = i * 256 + tid;
    int c = idx >> 3, r8 = (idx & 7) * 8;
    u16x8 v;
#pragma unroll
    for (int j = 0; j < 8; j++) v[j] = sh[r8 + j][c];
    *(u16x8*)(dst + (size_t)(ct * 64 + c) * R + rt * 64 + r8) = v;
  }
}

// ------------------------------------------------------- GEMM (fast path) ----
// C[i,n] = sum_k Arow(i)[k] * Bt[e][n][k]; A,Bt bf16 (Bt = K-major weights).
// m97 structure: BM=BN=128, BK=32, global_load_lds width 16 for A and B.
template <int K, int N, bool GATHER, bool GELU>
__global__ __launch_bounds__(256) void gemm_t_kernel(
    const u16* __restrict__ A, const u16* __restrict__ Bt, u16* __restrict__ C,
    const int* __restrict__ offsets, const int* __restrict__ perm) {
  __shared__ u16 As[128 * 32];   // [row][k] 8 KB
  __shared__ u16 Bs[128 * 32];   // [n][k]   8 KB
  int e = blockIdx.z;
  int off = offsets[e];
  int nrows = offsets[e + 1] - off;
  int mtile = blockIdx.y;
  if (mtile * 128 >= nrows) return;   // block-uniform: safe before barriers
  int ntile = blockIdx.x;

  int tid = threadIdx.x;
  int wave = tid >> 6, lane = tid & 63;

  int rr = tid >> 2;             // tile row handled by this thread's 16B chunk
  int kc = (tid & 3) * 8;        // k-offset (elements) of the chunk

  int m0 = mtile * 128 + rr;
  int mm0 = min(m0, nrows - 1);          // clamp: duplicates last valid row
  int mm1 = min(m0 + 64, nrows - 1);
  const u16 *arow0, *arow1;
  if (GATHER) {
    arow0 = A + (size_t)perm[off + mm0] * K + kc;
    arow1 = A + (size_t)perm[off + mm1] * K + kc;
  } else {
    arow0 = A + (size_t)(off + mm0) * K + kc;
    arow1 = A + (size_t)(off + mm1) * K + kc;
  }
  const u16* bbase = Bt + (size_t)e * ((size_t)N * K);
  const u16* brow0 = bbase + (size_t)(ntile * 128 + rr) * K + kc;
  const u16* brow1 = bbase + (size_t)(ntile * 128 + rr + 64) * K + kc;

  // wave-uniform LDS destinations: chunk index == tid (and tid+256)
  u16* asd0 = As + (size_t)(wave * 64) * 8;
  u16* asd1 = As + (size_t)(256 + wave * 64) * 8;
  u16* bsd0 = Bs + (size_t)(wave * 64) * 8;
  u16* bsd1 = Bs + (size_t)(256 + wave * 64) * 8;

  int wm = (wave >> 1) * 64, wn = (wave & 1) * 64;
  int lm = lane & 15, kq = lane >> 4;

  f32x4 acc[4][4];
  f32x4 zero = {0.f, 0.f, 0.f, 0.f};
#pragma unroll
  for (int i = 0; i < 4; i++)
#pragma unroll
    for (int j = 0; j < 4; j++) acc[i][j] = zero;

  for (int k0 = 0; k0 < K; k0 += 32) {
    async16(arow0 + k0, asd0);
    async16(arow1 + k0, asd1);
    async16(brow0 + k0, bsd0);
    async16(brow1 + k0, bsd1);
    __syncthreads();   // drains vmcnt -> staged tile visible
    short8 a[4], b[4];
#pragma unroll
    for (int i = 0; i < 4; i++) {
      a[i] = *(const short8*)(As + (size_t)(wm + i * 16 + lm) * 32 + kq * 8);
      b[i] = *(const short8*)(Bs + (size_t)(wn + i * 16 + lm) * 32 + kq * 8);
    }
#pragma unroll
    for (int i = 0; i < 4; i++)
#pragma unroll
      for (int j = 0; j < 4; j++)
        acc[i][j] = __builtin_amdgcn_mfma_f32_16x16x32_bf16(a[i], b[j], acc[i][j], 0, 0, 0);
    __syncthreads();   // protect LDS from next iteration's staging
  }

  // C/D frag: col = lane&15, row = (lane>>4)*4 + reg
#pragma unroll
  for (int i = 0; i < 4; i++) {
    int rbase = mtile * 128 + wm + i * 16 + kq * 4;
#pragma unroll
    for (int r = 0; r < 4; r++) {
      int row = rbase + r;
      if (row < nrows) {
        u16* crow = C + (size_t)(off + row) * N + ntile * 128 + wn + lm;
#pragma unroll
        for (int j = 0; j < 4; j++) {
          float v = acc[i][j][r];
          if (GELU) v = gelu_tanh(v);
          crow[j * 16] = f2bf(v);
        }
      }
    }
  }
}

// --------------------------------------------- GEMM (fallback, round-3) ----
// B is fp32 [K][N], converted+repacked in LDS. Used only if ws_size is small.
template <int K, int N, bool GATHER, bool GELU>
__global__ __launch_bounds__(256) void gemm_f_kernel(
    const u16* __restrict__ A, const float* __restrict__ B, u16* __restrict__ C,
    const int* __restrict__ offsets, const int* __restrict__ perm) {
  __shared__ u16 As[128 * 32];
  __shared__ u16 Bs[128 * 32];
  int e = blockIdx.z;
  int off = offsets[e];
  int nrows = offsets[e + 1] - off;
  int mtile = blockIdx.y;
  if (mtile * 128 >= nrows) return;
  int ntile = blockIdx.x;

  int tid = threadIdx.x;
  int wave = tid >> 6, lane = tid & 63;

  int rr = tid >> 2;
  int kc = (tid & 3) * 8;
  int m0 = mtile * 128 + rr;
  int mm0 = min(m0, nrows - 1);
  int mm1 = min(m0 + 64, nrows - 1);
  const u16 *arow0, *arow1;
  if (GATHER) {
    arow0 = A + (size_t)perm[off + mm0] * K + kc;
    arow1 = A + (size_t)perm[off + mm1] * K + kc;
  } else {
    arow0 = A + (size_t)(off + mm0) * K + kc;
    arow1 = A + (size_t)(off + mm1) * K + kc;
  }

  int kk2 = (tid >> 4) * 2;
  int n8  = (tid & 15) * 8;
  const float* brow0 = B + (size_t)e * ((size_t)K * N) + (size_t)kk2 * N
                         + (size_t)ntile * 128 + n8;
  const float* brow1 = brow0 + N;

  int wm = (wave >> 1) * 64, wn = (wave & 1) * 64;
  int lm = lane & 15, kq = lane >> 4;

  f32x4 acc[4][4];
  f32x4 zero = {0.f, 0.f, 0.f, 0.f};
#pragma unroll
  for (int i = 0; i < 4; i++)
#pragma unroll
    for (int j = 0; j < 4; j++) acc[i][j] = zero;

  uint32_t* bs32 = (uint32_t*)Bs;
  for (int k0 = 0; k0 < K; k0 += 32) {
    u16x8 av0 = *(const u16x8*)(arow0 + k0);
    u16x8 av1 = *(const u16x8*)(arow1 + k0);
    float4 b00 = *(const float4*)(brow0 + (size_t)k0 * N);
    float4 b01 = *(const float4*)(brow0 + (size_t)k0 * N + 4);
    float4 b10 = *(const float4*)(brow1 + (size_t)k0 * N);
    float4 b11 = *(const float4*)(brow1 + (size_t)k0 * N + 4);
    __syncthreads();
    *(u16x8*)(As + (size_t)rr * 32 + kc) = av0;
    *(u16x8*)(As + (size_t)(rr + 64) * 32 + kc) = av1;
    int wcol = kk2 >> 1;
    bs32[(size_t)(n8 + 0) * 16 + wcol] = (uint32_t)f2bf(b00.x) | ((uint32_t)f2bf(b10.x) << 16);
    bs32[(size_t)(n8 + 1) * 16 + wcol] = (uint32_t)f2bf(b00.y) | ((uint32_t)f2bf(b10.y) << 16);
    bs32[(size_t)(n8 + 2) * 16 + wcol] = (uint32_t)f2bf(b00.z) | ((uint32_t)f2bf(b10.z) << 16);
    bs32[(size_t)(n8 + 3) * 16 + wcol] = (uint32_t)f2bf(b00.w) | ((uint32_t)f2bf(b10.w) << 16);
    bs32[(size_t)(n8 + 4) * 16 + wcol] = (uint32_t)f2bf(b01.x) | ((uint32_t)f2bf(b11.x) << 16);
    bs32[(size_t)(n8 + 5) * 16 + wcol] = (uint32_t)f2bf(b01.y) | ((uint32_t)f2bf(b11.y) << 16);
    bs32[(size_t)(n8 + 6) * 16 + wcol] = (uint32_t)f2bf(b01.z) | ((uint32_t)f2bf(b11.z) << 16);
    bs32[(size_t)(n8 + 7) * 16 + wcol] = (uint32_t)f2bf(b01.w) | ((uint32_t)f2bf(b11.w) << 16);
    __syncthreads();
    short8 a[4], b[4];
#pragma unroll
    for (int i = 0; i < 4; i++) {
      a[i] = *(const short8*)(As + (size_t)(wm + i * 16 + lm) * 32 + kq * 8);
      b[i] = *(const short8*)(Bs + (size_t)(wn + i * 16 + lm) * 32 + kq * 8);
    }
#pragma unroll
    for (int i = 0; i < 4; i++)
#pragma unroll
      for (int j = 0; j < 4; j++)
        acc[i][j] = __builtin_amdgcn_mfma_f32_16x16x32_bf16(a[i], b[j], acc[i][j], 0, 0, 0);
  }

#pragma unroll
  for (int i = 0; i < 4; i++) {
    int rbase = mtile * 128 + wm + i * 16 + kq * 4;
#pragma unroll
    for (int r = 0; r < 4; r++) {
      int row = rbase + r;
      if (row < nrows) {
        u16* crow = C + (size_t)(off + row) * N + ntile * 128 + wn + lm;
#pragma unroll
        for (int j = 0; j < 4; j++) {
          float v = acc[i][j][r];
          if (GELU) v = gelu_tanh(v);
          crow[j * 16] = f2bf(v);
        }
      }
    }
  }
}

// --------------------------------------------------------------- combine ----
// out[t] = w0 * Y[row(t,0)] + w1 * Y[row(t,1)]   (fp32 output)
__global__ void combine_kernel(const u16* __restrict__ Y, const int* __restrict__ slotrow,
                               const float* __restrict__ topw, float* __restrict__ out) {
  int idx = blockIdx.x * 256 + threadIdx.x;   // 8192 tokens * 256 chunks of 4
  int t = idx >> 8;
  int c = (idx & 255) * 4;
  int g0 = slotrow[t * 2], g1 = slotrow[t * 2 + 1];
  float w0 = topw[t * 2], w1 = topw[t * 2 + 1];
  u16x4 y0 = *(const u16x4*)(Y + (size_t)g0 * DMODEL + c);
  u16x4 y1 = *(const u16x4*)(Y + (size_t)g1 * DMODEL + c);
  float4 o;
  o.x = w0 * bf2f(y0[0]) + w1 * bf2f(y1[0]);
  o.y = w0 * bf2f(y0[1]) + w1 * bf2f(y1[1]);
  o.z = w0 * bf2f(y0[2]) + w1 * bf2f(y1[2]);
  o.w = w0 * bf2f(y0[3]) + w1 * bf2f(y1[3]);
  *(float4*)(out + (size_t)t * DMODEL + c) = o;
}

// ---------------------------------------------------------------- launch ----
extern "C" void kernel_launch(void* const* d_in, const int* in_sizes, int n_in,
                              void* d_out, int out_size, void* d_ws, size_t ws_size,
                              hipStream_t stream) {
  const float* x  = (const float*)d_in[0];
  const float* Wg = (const float*)d_in[1];
  const float* w1 = (const float*)d_in[2];
  const float* w2 = (const float*)d_in[3];
  float* out = (float*)d_out;

  const size_t SZ_H   = (size_t)TASSIGN * FFN * 2;        // 128 MB
  const size_t SZ_W1T = (size_t)NEXP * FFN * DMODEL * 2;  //  64 MB (Y aliases: needs 32 MB)
  const size_t SZ_W2T = (size_t)NEXP * DMODEL * FFN * 2;  //  64 MB
  const size_t SZ_XB  = (size_t)T_TOK * DMODEL * 2;       //  16 MB
  const size_t SZ_Y   = (size_t)TASSIGN * DMODEL * 2;     //  32 MB
  const size_t SZ_SMALL = (size_t)TASSIGN * 4 * 4 + 4096;
  const size_t WS_FULL = SZ_H + SZ_W1T + SZ_W2T + SZ_XB + SZ_SMALL;   // ~272.3 MB

  uint8_t* ws = (uint8_t*)d_ws;
  bool fast = (ws_size >= WS_FULL);

  size_t o = 0;
  u16* H = (u16*)(ws + o); o += SZ_H;
  u16 *w1t = nullptr, *w2t = nullptr, *Y;
  if (fast) {
    w1t = (u16*)(ws + o); o += SZ_W1T;
    w2t = (u16*)(ws + o); o += SZ_W2T;
    Y = w1t;                       // w1t is dead once GEMM2 starts writing Y
  } else {
    Y = (u16*)(ws + o); o += SZ_Y;
  }
  u16* xb = (u16*)(ws + o); o += SZ_XB;
  int*   topi    = (int*)(ws + o);   o += (size_t)TASSIGN * 4;
  float* topw    = (float*)(ws + o); o += (size_t)TASSIGN * 4;
  int*   perm    = (int*)(ws + o);   o += (size_t)TASSIGN * 4;
  int*   slotrow = (int*)(ws + o);   o += (size_t)TASSIGN * 4;
  int*   meta    = (int*)(ws + o);
  int* counts = meta, *offsets = meta + 8, *cursors = meta + 17;

  init_kernel<<<1, 64, 0, stream>>>(meta);
  gate_kernel<<<T_TOK / 4, 256, 0, stream>>>(x, Wg, topi, topw, counts, xb);
  scan_kernel<<<1, 64, 0, stream>>>(counts, offsets, cursors);
  build_kernel<<<T_TOK / 256, 256, 0, stream>>>(topi, offsets, cursors, perm, slotrow);

  if (fast) {
    transpose_kernel<<<dim3(1024, 16), 256, 0, stream>>>(w1, w2, w1t, w2t);
    gemm_t_kernel<DMODEL, FFN, true, true>
        <<<dim3(FFN / 128, 64, NEXP), 256, 0, stream>>>(xb, w1t, H, offsets, perm);
    gemm_t_kernel<FFN, DMODEL, false, false>
        <<<dim3(DMODEL / 128, 64, NEXP), 256, 0, stream>>>(H, w2t, Y, offsets, perm);
  } else {
    gemm_f_kernel<DMODEL, FFN, true, true>
        <<<dim3(FFN / 128, 64, NEXP), 256, 0, stream>>>(xb, w1, H, offsets, perm);
    gemm_f_kernel<FFN, DMODEL, false, false>
        <<<dim3(DMODEL / 128, 64, NEXP), 256, 0, stream>>>(H, w2, Y, offsets, perm);
  }
  combine_kernel<<<(T_TOK * DMODEL / 4) / 256, 256, 0, stream>>>(Y, slotrow, topw, out);
}